// Round 4
// baseline (1018.338 us; speedup 1.0000x reference)
//
#include <hip/hip_runtime.h>
#include <math.h>

#define Bsz 4
#define Cch 32
#define Hh 48
#define Ww 48
#define HWsz 2304          // 48*48
#define BHW 9216           // 4*2304
#define CIN_CAT 96
#define NSPLIT 16          // column splits for max partials (4 per b-group)
#define TILES_PER_SPLIT 36 // 576 col-tiles / 16

typedef __bf16 bf16_t;
typedef __bf16 bf16x8 __attribute__((ext_vector_type(8)));
typedef float f32x4 __attribute__((ext_vector_type(4)));

// ---------------- bilinear resize, align_corners=True ----------------
__global__ void resize_kernel(const float* __restrict__ in, float* __restrict__ out,
                              int inH, int inW, int rowStride, int chanStride, int baseOff,
                              float scaleY, float scaleX, int outCtot, int chanOff) {
    int idx = blockIdx.x * blockDim.x + threadIdx.x;
    if (idx >= Bsz * Cch * HWsz) return;
    int x = idx % Ww;
    int y = (idx / Ww) % Hh;
    int c = (idx / HWsz) % Cch;
    int b = idx / (HWsz * Cch);
    float fy = y * scaleY;
    float fx = x * scaleX;
    int y0 = (int)floorf(fy); int x0 = (int)floorf(fx);
    y0 = min(y0, inH - 1); x0 = min(x0, inW - 1);
    int y1 = min(y0 + 1, inH - 1); int x1 = min(x0 + 1, inW - 1);
    float wy = fy - (float)y0, wx = fx - (float)x0;
    const float* src = in + (size_t)(b * Cch + c) * chanStride + baseOff;
    float v00 = src[y0 * rowStride + x0];
    float v01 = src[y0 * rowStride + x1];
    float v10 = src[y1 * rowStride + x0];
    float v11 = src[y1 * rowStride + x1];
    float top = v00 * (1.f - wx) + v01 * wx;
    float bot = v10 * (1.f - wx) + v11 * wx;
    float r = top * (1.f - wy) + bot * wy;
    out[((size_t)(b * outCtot) + c + chanOff) * HWsz + y * Ww + x] = r;
}

// copy x1 (B,32,HW) into cat channels [64..96)
__global__ void copy_x1_kernel(const float* __restrict__ x1, float* __restrict__ cat) {
    int idx = blockIdx.x * blockDim.x + threadIdx.x;
    if (idx >= Bsz * Cch * HWsz) return;
    int hw = idx % HWsz;
    int c = (idx / HWsz) % Cch;
    int b = idx / (HWsz * Cch);
    cat[((size_t)(b * CIN_CAT) + 64 + c) * HWsz + hw] = x1[idx];
}

// ---------------- 3x3 conv, pad 1, all-Cout-per-thread, fused BN ----------------
// Thread = one pixel; computes ALL COUT channels (acc in VGPRs). Input taps are
// read once per ci and reused across COUT -> FMA:load = 9*COUT : 9. Weights are
// wave-uniform -> scalar loads. Grid = BHW/64 blocks of 64 threads.
template<int CIN, int COUT, bool HAS2, bool HASRES>
__global__ void conv3x3_all(const float* __restrict__ in, const float* __restrict__ in2,
                            const float* __restrict__ w, const float* __restrict__ bng,
                            const float* __restrict__ bnb, const float* __restrict__ res,
                            float* __restrict__ out) {
    int p = blockIdx.x * 64 + threadIdx.x;   // pixel 0..9215
    int b = p / HWsz;
    int hw = p % HWsz;
    int y = hw / Ww;
    int x = hw % Ww;
    int off[9];
    float vm[9];
#pragma unroll
    for (int t = 0; t < 9; ++t) {
        int iy = y + t / 3 - 1;
        int ix = x + t % 3 - 1;
        bool v = (iy >= 0 && iy < Hh && ix >= 0 && ix < Ww);
        off[t] = v ? iy * Ww + ix : hw;   // clamped (safe) address
        vm[t] = v ? 1.0f : 0.0f;
    }
    const float* base = in + (size_t)b * CIN * HWsz;
    const float* base2 = HAS2 ? in2 + (size_t)b * CIN * HWsz : nullptr;
    float acc[COUT];
#pragma unroll
    for (int co = 0; co < COUT; ++co) acc[co] = 0.f;
#pragma unroll 2
    for (int ci = 0; ci < CIN; ++ci) {
        float tv[9];
#pragma unroll
        for (int t = 0; t < 9; ++t) {
            float v = base[(size_t)ci * HWsz + off[t]];
            if (HAS2) v += base2[(size_t)ci * HWsz + off[t]];
            tv[t] = v * vm[t];
        }
#pragma unroll
        for (int co = 0; co < COUT; ++co) {
            const float* wp = w + ((size_t)co * CIN + ci) * 9;
#pragma unroll
            for (int t = 0; t < 9; ++t) acc[co] = fmaf(tv[t], wp[t], acc[co]);
        }
    }
    float bscale = rsqrtf(1.0f + 1e-5f);
#pragma unroll
    for (int co = 0; co < COUT; ++co) {
        float r = acc[co] * (bng[co] * bscale) + bnb[co];
        size_t oidx = ((size_t)(b * COUT) + co) * HWsz + hw;
        if (HASRES) r += res[oidx];
        out[oidx] = r;
    }
}

// ---------------- SA: fused 1x1 convs for q, k, c(no-bias) ----------------
// blockIdx.y: 0 -> q (fp32 natural + bf16 hi/lo), 1 -> k (col-contig kT fp32 + hi/lo),
//             2 -> c no-bias (natural fp32)
__global__ void qkc_kernel(const float* __restrict__ x,
                           const float* __restrict__ qw, const float* __restrict__ qb,
                           const float* __restrict__ kw, const float* __restrict__ kb,
                           const float* __restrict__ cw,
                           float* __restrict__ qbuf, float* __restrict__ kT,
                           float* __restrict__ cnb,
                           bf16_t* __restrict__ qhi, bf16_t* __restrict__ qlo,
                           bf16_t* __restrict__ khi, bf16_t* __restrict__ klo) {
    int p = blockIdx.x * blockDim.x + threadIdx.x;  // pixel 0..9215
    if (p >= BHW) return;
    int b = p / HWsz;
    int hw = p % HWsz;
    float xin[Cch];
#pragma unroll
    for (int ci = 0; ci < Cch; ++ci) xin[ci] = x[((size_t)(b * Cch) + ci) * HWsz + hw];
    int which = blockIdx.y;
    if (which == 0) {
        for (int co = 0; co < Cch; ++co) {
            float acc = qb[co];
#pragma unroll
            for (int ci = 0; ci < Cch; ++ci) acc += xin[ci] * qw[co * Cch + ci];
            size_t f = ((size_t)(b * Cch) + co) * HWsz + hw;
            qbuf[f] = acc;
            bf16_t h = (bf16_t)acc;
            qhi[f] = h;
            qlo[f] = (bf16_t)(acc - (float)h);
        }
    } else if (which == 1) {
        for (int co = 0; co < Cch; ++co) {
            float acc = kb[co];
#pragma unroll
            for (int ci = 0; ci < Cch; ++ci) acc += xin[ci] * kw[co * Cch + ci];
            size_t f = (size_t)p * Cch + co;
            kT[f] = acc;
            bf16_t h = (bf16_t)acc;
            khi[f] = h;
            klo[f] = (bf16_t)(acc - (float)h);
        }
    } else {
        for (int co = 0; co < Cch; ++co) {
            float acc = 0.f;
#pragma unroll
            for (int ci = 0; ci < Cch; ++ci) acc += xin[ci] * cw[co * Cch + ci];
            cnb[((size_t)(b * Cch) + co) * HWsz + hw] = acc;
        }
    }
}

// ---------------- ksum: column sums of kT (exact fp32, for the mean term) ----------
__global__ void ksum_kernel(const float* __restrict__ kT, float* __restrict__ ksum) {
    int c = blockIdx.x;   // 0..31
    int tid = threadIdx.x;
    __shared__ float red[256];
    float s = 0.f;
    for (int j = tid; j < BHW; j += 256) s += kT[(size_t)j * Cch + c];
    red[tid] = s; __syncthreads();
    for (int st = 128; st > 0; st >>= 1) { if (tid < st) red[tid] += red[tid + st]; __syncthreads(); }
    if (tid == 0) ksum[c] = red[0];
}

// ---------------- score max-scan via MFMA (split-bf16: hi*hi + hi*lo + lo*hi) -------
__global__ void score_mfma_kernel(const bf16_t* __restrict__ qhi, const bf16_t* __restrict__ qlo,
                                  const bf16_t* __restrict__ khi, const bf16_t* __restrict__ klo,
                                  float* __restrict__ pmax) {
    int wave = threadIdx.x >> 6;
    int lane = threadIdx.x & 63;
    int rt = blockIdx.x * 4 + wave;   // 0..575
    int cs = blockIdx.y;              // 0..15
    int lrow = lane & 15;
    int lk = lane >> 4;
    size_t aoff = (size_t)(rt * 16 + lrow) * Cch + lk * 8;
    bf16x8 ahi = *(const bf16x8*)(qhi + aoff);
    bf16x8 alo = *(const bf16x8*)(qlo + aoff);
    f32x4 mx = {-1e30f, -1e30f, -1e30f, -1e30f};
    int ct0 = cs * TILES_PER_SPLIT;
    for (int ct = ct0; ct < ct0 + TILES_PER_SPLIT; ++ct) {
        size_t boff = (size_t)(ct * 16 + lrow) * Cch + lk * 8;
        bf16x8 bhi = *(const bf16x8*)(khi + boff);
        bf16x8 blo = *(const bf16x8*)(klo + boff);
        f32x4 d = {0.f, 0.f, 0.f, 0.f};
        d = __builtin_amdgcn_mfma_f32_16x16x32_bf16(ahi, bhi, d, 0, 0, 0);
        d = __builtin_amdgcn_mfma_f32_16x16x32_bf16(ahi, blo, d, 0, 0, 0);
        d = __builtin_amdgcn_mfma_f32_16x16x32_bf16(alo, bhi, d, 0, 0, 0);
#pragma unroll
        for (int r = 0; r < 4; ++r) mx[r] = fmaxf(mx[r], d[r]);
    }
#pragma unroll
    for (int off = 1; off < 16; off <<= 1) {
#pragma unroll
        for (int r = 0; r < 4; ++r) {
            float o = __shfl_xor(mx[r], off, 64);
            mx[r] = fmaxf(mx[r], o);
        }
    }
    if (lrow == 0) {
#pragma unroll
        for (int r = 0; r < 4; ++r) {
            int row = rt * 16 + lk * 4 + r;   // C/D layout: row=(lane>>4)*4+reg
            pmax[(size_t)cs * BHW + row] = mx[r];
        }
    }
}

// ---------------- logits: mean_b(max) + q.ksum/BHW, scaled ----------------
__global__ void logits_kernel(const float* __restrict__ qbuf, const float* __restrict__ ksum,
                              const float* __restrict__ pmax, float* __restrict__ logits) {
    __shared__ float ks[Cch];
    if (threadIdx.x < Cch) ks[threadIdx.x] = ksum[threadIdx.x];
    __syncthreads();
    int i = blockIdx.x * 256 + threadIdx.x;
    if (i >= BHW) return;
    float msum = 0.f;
#pragma unroll
    for (int b = 0; b < 4; ++b) {
        float m = -1e30f;
#pragma unroll
        for (int k = 0; k < 4; ++k) m = fmaxf(m, pmax[(size_t)(b * 4 + k) * BHW + i]);
        msum += m;
    }
    float dot = 0.f;
    const float4* qp = (const float4*)(qbuf + (size_t)i * Cch);
#pragma unroll
    for (int t = 0; t < 8; ++t) {
        float4 v = qp[t];
        dot += v.x * ks[4 * t] + v.y * ks[4 * t + 1] + v.z * ks[4 * t + 2] + v.w * ks[4 * t + 3];
    }
    logits[i] = (msum * 0.25f + dot * (1.0f / (float)BHW)) * 0.17677669529663687f;
}

// softmax over HW per b -> xco
__global__ void softmax_kernel(const float* __restrict__ logits, float* __restrict__ xco) {
    int b = blockIdx.x;
    int tid = threadIdx.x;
    __shared__ float red[256];
    const float* l = logits + (size_t)b * HWsz;
    float m = -1e30f;
    for (int h = tid; h < HWsz; h += 256) m = fmaxf(m, l[h]);
    red[tid] = m; __syncthreads();
    for (int s = 128; s > 0; s >>= 1) { if (tid < s) red[tid] = fmaxf(red[tid], red[tid + s]); __syncthreads(); }
    m = red[0]; __syncthreads();
    float s = 0.f;
    for (int h = tid; h < HWsz; h += 256) s += expf(l[h] - m);
    red[tid] = s; __syncthreads();
    for (int st = 128; st > 0; st >>= 1) { if (tid < st) red[tid] += red[tid + st]; __syncthreads(); }
    float inv = 1.0f / red[0];
    for (int h = tid; h < HWsz; h += 256) xco[(size_t)b * HWsz + h] = expf(l[h] - m) * inv;
}

// out[b,c,hw] = cnb[b,c,hw] * xco[b,hw] + cb[c]
__global__ void sa_apply_kernel(const float* __restrict__ cnb, const float* __restrict__ xco,
                                const float* __restrict__ cb, float* __restrict__ out) {
    int idx = blockIdx.x * blockDim.x + threadIdx.x;
    if (idx >= Bsz * Cch * HWsz) return;
    int hw = idx % HWsz;
    int c = (idx / HWsz) % Cch;
    int b = idx / (HWsz * Cch);
    out[idx] = cnb[idx] * xco[(size_t)b * HWsz + hw] + cb[c];
}

extern "C" void kernel_launch(void* const* d_in, const int* in_sizes, int n_in,
                              void* d_out, int out_size, void* d_ws, size_t ws_size,
                              hipStream_t stream) {
    const float* x1      = (const float*)d_in[0];
    const float* x2      = (const float*)d_in[1];
    const float* x3      = (const float*)d_in[2];
    const float* conv1_w = (const float*)d_in[3];
    const float* bn1_g   = (const float*)d_in[4];
    const float* bn1_b   = (const float*)d_in[5];
    const float* conv4_w = (const float*)d_in[6];
    const float* bn4_g   = (const float*)d_in[7];
    const float* bn4_b   = (const float*)d_in[8];
    const float* conv5_w = (const float*)d_in[9];
    const float* bn5_g   = (const float*)d_in[10];
    const float* bn5_b   = (const float*)d_in[11];
    const float* convfs_w= (const float*)d_in[12];
    const float* bnfs_g  = (const float*)d_in[13];
    const float* bnfs_b  = (const float*)d_in[14];
    const float* saq_w   = (const float*)d_in[15];
    const float* saq_b   = (const float*)d_in[16];
    const float* sak_w   = (const float*)d_in[17];
    const float* sak_b   = (const float*)d_in[18];
    const float* sac6_w  = (const float*)d_in[19];
    const float* sac6_b  = (const float*)d_in[20];

    float* ws = (float*)d_ws;
    const size_t TEN = (size_t)Bsz * Cch * HWsz;  // 294912
    float* cat    = ws;                    // B*96*HW = 884736
    float* f1     = cat + (size_t)Bsz * CIN_CAT * HWsz;
    float* f_s_1  = f1 + TEN;
    float* fg     = f_s_1 + TEN;
    float* fs     = fg + TEN;
    float* sfs    = fs + TEN;
    float* fgl    = sfs + TEN;
    float* t1     = fgl + TEN;
    float* qbuf   = t1 + TEN;
    float* kT     = qbuf + TEN;
    float* cnb    = kT + TEN;
    float* logits = cnb + TEN;             // 9216
    float* xco    = logits + BHW;          // 9216
    float* pmax   = xco + BHW;             // 16*9216
    float* ksum   = pmax + (size_t)NSPLIT * BHW;  // 32
    bf16_t* qhi   = (bf16_t*)(ksum + 64);  // 294912 bf16 each
    bf16_t* qlo   = qhi + TEN;
    bf16_t* khi   = qlo + TEN;
    bf16_t* klo   = khi + TEN;

    const int TPB = 256;
    const int GRID_TEN = (int)((TEN + TPB - 1) / TPB);   // 1152
    const int GRID_PIX = BHW / 64;                        // 144

    // 1. f3 = resize(x3, 192->48) into cat ch[0:32)
    resize_kernel<<<GRID_TEN, TPB, 0, stream>>>(x3, cat, 192, 192, 192, 192 * 192, 0,
                                                191.0f / 47.0f, 191.0f / 47.0f, CIN_CAT, 0);
    // 2. f2 = resize(x2, 96->48) into cat ch[32:64)
    resize_kernel<<<GRID_TEN, TPB, 0, stream>>>(x2, cat, 96, 96, 96, 96 * 96, 0,
                                                95.0f / 47.0f, 95.0f / 47.0f, CIN_CAT, 32);
    // 3. x1 into cat ch[64:96)
    copy_x1_kernel<<<GRID_TEN, TPB, 0, stream>>>(x1, cat);
    // 4. f1 = bn1(conv1(cat))
    conv3x3_all<CIN_CAT, Cch, false, false><<<GRID_PIX, 64, 0, stream>>>(
        cat, nullptr, conv1_w, bn1_g, bn1_b, nullptr, f1);
    // 5. f_s_1 = resize(f1[:, :, 32:48, 32:48], 16->48)  (chunk idx is always 8)
    resize_kernel<<<GRID_TEN, TPB, 0, stream>>>(f1, f_s_1, 16, 16, Ww, HWsz, 32 * Ww + 32,
                                                15.0f / 47.0f, 15.0f / 47.0f, Cch, 0);

    // SA macro: x -> out
    auto run_sa = [&](const float* xin, float* outp) {
        dim3 g1((BHW + TPB - 1) / TPB, 3);
        qkc_kernel<<<g1, TPB, 0, stream>>>(xin, saq_w, saq_b, sak_w, sak_b, sac6_w,
                                           qbuf, kT, cnb, qhi, qlo, khi, klo);
        ksum_kernel<<<Cch, 256, 0, stream>>>(kT, ksum);
        dim3 g2(144, NSPLIT);
        score_mfma_kernel<<<g2, 256, 0, stream>>>(qhi, qlo, khi, klo, pmax);
        logits_kernel<<<BHW / 256, 256, 0, stream>>>(qbuf, ksum, pmax, logits);
        softmax_kernel<<<Bsz, 256, 0, stream>>>(logits, xco);
        sa_apply_kernel<<<GRID_TEN, TPB, 0, stream>>>(cnb, xco, sac6_b, outp);
    };

    // 6-8. fg = sa(f1); fs = sa(f_s_1); sfs = sa(fs)
    run_sa(f1, fg);
    run_sa(f_s_1, fs);
    run_sa(fs, sfs);

    // 9. fgl = bnfs(convfs(fg + sfs))
    conv3x3_all<Cch, Cch, true, false><<<GRID_PIX, 64, 0, stream>>>(
        fg, sfs, convfs_w, bnfs_g, bnfs_b, nullptr, fgl);
    // 10. t1 = bn4(conv4(fgl)) + fg
    conv3x3_all<Cch, Cch, false, true><<<GRID_PIX, 64, 0, stream>>>(
        fgl, nullptr, conv4_w, bn4_g, bn4_b, fg, t1);
    // 11. out = bn5(conv5(t1))   (B,1,48,48)
    conv3x3_all<Cch, 1, false, false><<<GRID_PIX, 64, 0, stream>>>(
        t1, nullptr, conv5_w, bn5_g, bn5_b, nullptr, (float*)d_out);
}

// Round 7
// 914.753 us; speedup vs baseline: 1.1132x; 1.1132x over previous
//
#include <hip/hip_runtime.h>
#include <math.h>

#define Bsz 4
#define Cch 32
#define Hh 48
#define Ww 48
#define HWsz 2304          // 48*48
#define BHW 9216           // 4*2304
#define CIN_CAT 96
#define NSPLIT 16          // column splits for max partials (4 per b-group)
#define TILES_PER_SPLIT 36 // 576 col-tiles / 16

typedef __bf16 bf16_t;
typedef __bf16 bf16x8 __attribute__((ext_vector_type(8)));
typedef float f32x4 __attribute__((ext_vector_type(4)));

// ---------------- bilinear resize, align_corners=True ----------------
__global__ void resize_kernel(const float* __restrict__ in, float* __restrict__ out,
                              int inH, int inW, int rowStride, int chanStride, int baseOff,
                              float scaleY, float scaleX, int outCtot, int chanOff) {
    int idx = blockIdx.x * blockDim.x + threadIdx.x;
    if (idx >= Bsz * Cch * HWsz) return;
    int x = idx % Ww;
    int y = (idx / Ww) % Hh;
    int c = (idx / HWsz) % Cch;
    int b = idx / (HWsz * Cch);
    float fy = y * scaleY;
    float fx = x * scaleX;
    int y0 = (int)floorf(fy); int x0 = (int)floorf(fx);
    y0 = min(y0, inH - 1); x0 = min(x0, inW - 1);
    int y1 = min(y0 + 1, inH - 1); int x1 = min(x0 + 1, inW - 1);
    float wy = fy - (float)y0, wx = fx - (float)x0;
    const float* src = in + (size_t)(b * Cch + c) * chanStride + baseOff;
    float v00 = src[y0 * rowStride + x0];
    float v01 = src[y0 * rowStride + x1];
    float v10 = src[y1 * rowStride + x0];
    float v11 = src[y1 * rowStride + x1];
    float top = v00 * (1.f - wx) + v01 * wx;
    float bot = v10 * (1.f - wx) + v11 * wx;
    float r = top * (1.f - wy) + bot * wy;
    out[((size_t)(b * outCtot) + c + chanOff) * HWsz + y * Ww + x] = r;
}

// copy x1 (B,32,HW) into cat channels [64..96)
__global__ void copy_x1_kernel(const float* __restrict__ x1, float* __restrict__ cat) {
    int idx = blockIdx.x * blockDim.x + threadIdx.x;
    if (idx >= Bsz * Cch * HWsz) return;
    int hw = idx % HWsz;
    int c = (idx / HWsz) % Cch;
    int b = idx / (HWsz * Cch);
    cat[((size_t)(b * CIN_CAT) + 64 + c) * HWsz + hw] = x1[idx];
}

// ---------------- 3x3 conv, pad 1, LDS-tiled, fused BN ----------------
// Block = 8x16 pixel tile x COSPLIT co-groups (threads = 128*COSPLIT).
// Input tile (10x18 with halo, zero-padded) staged in LDS per 32-ci chunk;
// each thread computes COUT/COSPLIT channels for its pixel from LDS.
// Weights are wave-uniform (co-group constant per wave) -> scalar loads.
// Grid = Bsz * 6 * 3 = 72 blocks.
template<int CIN, int COUT, int COSPLIT, bool HAS2, bool HASRES>
__global__ void conv3x3_tile(const float* __restrict__ in, const float* __restrict__ in2,
                             const float* __restrict__ w, const float* __restrict__ bng,
                             const float* __restrict__ bnb, const float* __restrict__ res,
                             float* __restrict__ out) {
    constexpr int TH = 8, TW = 16;
    constexpr int CHUNK = (CIN > 32) ? 32 : CIN;
    constexpr int NCH = CIN / CHUNK;
    constexpr int COG = COUT / COSPLIT;      // co per thread
    constexpr int NTHR = TH * TW * COSPLIT;
    __shared__ float lds[CHUNK][TH + 2][TW + 2];
    int bx = blockIdx.x % 3;
    int by = (blockIdx.x / 3) % 6;
    int b  = blockIdx.x / 18;
    int tid = threadIdx.x;
    int half = tid / (TH * TW);              // wave-uniform (128 = 2 waves per group)
    int pid = tid % (TH * TW);
    int px = pid % TW, py = pid / TW;
    int x0 = bx * TW, y0 = by * TH;
    float acc[COG];
#pragma unroll
    for (int g = 0; g < COG; ++g) acc[g] = 0.f;
    const float* base = in + (size_t)b * CIN * HWsz;
    const float* base2 = HAS2 ? in2 + (size_t)b * CIN * HWsz : nullptr;
    for (int ch = 0; ch < NCH; ++ch) {
        constexpr int NELEM = CHUNK * (TH + 2) * (TW + 2);
        if (ch > 0) __syncthreads();         // protect LDS reuse across chunks
        for (int i = tid; i < NELEM; i += NTHR) {
            int lx = i % (TW + 2);
            int rem = i / (TW + 2);
            int ly = rem % (TH + 2);
            int ci = rem / (TH + 2);
            int gx = x0 + lx - 1, gy = y0 + ly - 1;
            float v = 0.f;
            if (gx >= 0 && gx < Ww && gy >= 0 && gy < Hh) {
                size_t gi = (size_t)(ch * CHUNK + ci) * HWsz + gy * Ww + gx;
                v = base[gi];
                if (HAS2) v += base2[gi];
            }
            lds[ci][ly][lx] = v;
        }
        __syncthreads();
#pragma unroll 4
        for (int ci = 0; ci < CHUNK; ++ci) {
            float tv[9];
#pragma unroll
            for (int t = 0; t < 9; ++t) tv[t] = lds[ci][py + t / 3][px + t % 3];
#pragma unroll
            for (int g = 0; g < COG; ++g) {
                int co = half * COG + g;
                const float* wp = w + ((size_t)co * CIN + ch * CHUNK + ci) * 9;
#pragma unroll
                for (int t = 0; t < 9; ++t) acc[g] = fmaf(tv[t], wp[t], acc[g]);
            }
        }
    }
    float bscale = rsqrtf(1.0f + 1e-5f);
    int hw = (y0 + py) * Ww + (x0 + px);
#pragma unroll
    for (int g = 0; g < COG; ++g) {
        int co = half * COG + g;
        float r = acc[g] * (bng[co] * bscale) + bnb[co];
        size_t oidx = ((size_t)(b * COUT) + co) * HWsz + hw;
        if (HASRES) r += res[oidx];
        out[oidx] = r;
    }
}

// ---------------- SA: fused 1x1 convs for q, k, c(no-bias) ----------------
__global__ void qkc_kernel(const float* __restrict__ x,
                           const float* __restrict__ qw, const float* __restrict__ qb,
                           const float* __restrict__ kw, const float* __restrict__ kb,
                           const float* __restrict__ cw,
                           float* __restrict__ qbuf, float* __restrict__ kT,
                           float* __restrict__ cnb,
                           bf16_t* __restrict__ qhi, bf16_t* __restrict__ qlo,
                           bf16_t* __restrict__ khi, bf16_t* __restrict__ klo) {
    int p = blockIdx.x * blockDim.x + threadIdx.x;  // pixel 0..9215
    if (p >= BHW) return;
    int b = p / HWsz;
    int hw = p % HWsz;
    float xin[Cch];
#pragma unroll
    for (int ci = 0; ci < Cch; ++ci) xin[ci] = x[((size_t)(b * Cch) + ci) * HWsz + hw];
    int which = blockIdx.y;
    if (which == 0) {
        for (int co = 0; co < Cch; ++co) {
            float acc = qb[co];
#pragma unroll
            for (int ci = 0; ci < Cch; ++ci) acc += xin[ci] * qw[co * Cch + ci];
            size_t f = ((size_t)(b * Cch) + co) * HWsz + hw;
            qbuf[f] = acc;
            bf16_t h = (bf16_t)acc;
            qhi[f] = h;
            qlo[f] = (bf16_t)(acc - (float)h);
        }
    } else if (which == 1) {
        for (int co = 0; co < Cch; ++co) {
            float acc = kb[co];
#pragma unroll
            for (int ci = 0; ci < Cch; ++ci) acc += xin[ci] * kw[co * Cch + ci];
            size_t f = (size_t)p * Cch + co;
            kT[f] = acc;
            bf16_t h = (bf16_t)acc;
            khi[f] = h;
            klo[f] = (bf16_t)(acc - (float)h);
        }
    } else {
        for (int co = 0; co < Cch; ++co) {
            float acc = 0.f;
#pragma unroll
            for (int ci = 0; ci < Cch; ++ci) acc += xin[ci] * cw[co * Cch + ci];
            cnb[((size_t)(b * Cch) + co) * HWsz + hw] = acc;
        }
    }
}

// ---------------- ksum: column sums of kT (exact fp32, for the mean term) ----------
__global__ void ksum_kernel(const float* __restrict__ kT, float* __restrict__ ksum) {
    int c = blockIdx.x;   // 0..31
    int tid = threadIdx.x;
    __shared__ float red[256];
    float s = 0.f;
    for (int j = tid; j < BHW; j += 256) s += kT[(size_t)j * Cch + c];
    red[tid] = s; __syncthreads();
    for (int st = 128; st > 0; st >>= 1) { if (tid < st) red[tid] += red[tid + st]; __syncthreads(); }
    if (tid == 0) ksum[c] = red[0];
}

// ---------------- score max-scan via MFMA (split-bf16: hi*hi + hi*lo + lo*hi) -------
__global__ void score_mfma_kernel(const bf16_t* __restrict__ qhi, const bf16_t* __restrict__ qlo,
                                  const bf16_t* __restrict__ khi, const bf16_t* __restrict__ klo,
                                  float* __restrict__ pmax) {
    int wave = threadIdx.x >> 6;
    int lane = threadIdx.x & 63;
    int rt = blockIdx.x * 4 + wave;   // 0..575
    int cs = blockIdx.y;              // 0..15
    int lrow = lane & 15;
    int lk = lane >> 4;
    size_t aoff = (size_t)(rt * 16 + lrow) * Cch + lk * 8;
    bf16x8 ahi = *(const bf16x8*)(qhi + aoff);
    bf16x8 alo = *(const bf16x8*)(qlo + aoff);
    f32x4 mx = {-1e30f, -1e30f, -1e30f, -1e30f};
    int ct0 = cs * TILES_PER_SPLIT;
    for (int ct = ct0; ct < ct0 + TILES_PER_SPLIT; ++ct) {
        size_t boff = (size_t)(ct * 16 + lrow) * Cch + lk * 8;
        bf16x8 bhi = *(const bf16x8*)(khi + boff);
        bf16x8 blo = *(const bf16x8*)(klo + boff);
        f32x4 d = {0.f, 0.f, 0.f, 0.f};
        d = __builtin_amdgcn_mfma_f32_16x16x32_bf16(ahi, bhi, d, 0, 0, 0);
        d = __builtin_amdgcn_mfma_f32_16x16x32_bf16(ahi, blo, d, 0, 0, 0);
        d = __builtin_amdgcn_mfma_f32_16x16x32_bf16(alo, bhi, d, 0, 0, 0);
#pragma unroll
        for (int r = 0; r < 4; ++r) mx[r] = fmaxf(mx[r], d[r]);
    }
#pragma unroll
    for (int off = 1; off < 16; off <<= 1) {
#pragma unroll
        for (int r = 0; r < 4; ++r) {
            float o = __shfl_xor(mx[r], off, 64);
            mx[r] = fmaxf(mx[r], o);
        }
    }
    if (lrow == 0) {
#pragma unroll
        for (int r = 0; r < 4; ++r) {
            int row = rt * 16 + lk * 4 + r;   // C/D layout: row=(lane>>4)*4+reg
            pmax[(size_t)cs * BHW + row] = mx[r];
        }
    }
}

// ---------------- logits: mean_b(max) + q.ksum/BHW, scaled ----------------
__global__ void logits_kernel(const float* __restrict__ qbuf, const float* __restrict__ ksum,
                              const float* __restrict__ pmax, float* __restrict__ logits) {
    __shared__ float ks[Cch];
    if (threadIdx.x < Cch) ks[threadIdx.x] = ksum[threadIdx.x];
    __syncthreads();
    int i = blockIdx.x * 256 + threadIdx.x;
    if (i >= BHW) return;
    float msum = 0.f;
#pragma unroll
    for (int b = 0; b < 4; ++b) {
        float m = -1e30f;
#pragma unroll
        for (int k = 0; k < 4; ++k) m = fmaxf(m, pmax[(size_t)(b * 4 + k) * BHW + i]);
        msum += m;
    }
    float dot = 0.f;
    const float4* qp = (const float4*)(qbuf + (size_t)i * Cch);
#pragma unroll
    for (int t = 0; t < 8; ++t) {
        float4 v = qp[t];
        dot += v.x * ks[4 * t] + v.y * ks[4 * t + 1] + v.z * ks[4 * t + 2] + v.w * ks[4 * t + 3];
    }
    logits[i] = (msum * 0.25f + dot * (1.0f / (float)BHW)) * 0.17677669529663687f;
}

// softmax over HW per b -> xco
__global__ void softmax_kernel(const float* __restrict__ logits, float* __restrict__ xco) {
    int b = blockIdx.x;
    int tid = threadIdx.x;
    __shared__ float red[256];
    const float* l = logits + (size_t)b * HWsz;
    float m = -1e30f;
    for (int h = tid; h < HWsz; h += 256) m = fmaxf(m, l[h]);
    red[tid] = m; __syncthreads();
    for (int s = 128; s > 0; s >>= 1) { if (tid < s) red[tid] = fmaxf(red[tid], red[tid + s]); __syncthreads(); }
    m = red[0]; __syncthreads();
    float s = 0.f;
    for (int h = tid; h < HWsz; h += 256) s += expf(l[h] - m);
    red[tid] = s; __syncthreads();
    for (int st = 128; st > 0; st >>= 1) { if (tid < st) red[tid] += red[tid + st]; __syncthreads(); }
    float inv = 1.0f / red[0];
    for (int h = tid; h < HWsz; h += 256) xco[(size_t)b * HWsz + h] = expf(l[h] - m) * inv;
}

// out[b,c,hw] = cnb[b,c,hw] * xco[b,hw] + cb[c]
__global__ void sa_apply_kernel(const float* __restrict__ cnb, const float* __restrict__ xco,
                                const float* __restrict__ cb, float* __restrict__ out) {
    int idx = blockIdx.x * blockDim.x + threadIdx.x;
    if (idx >= Bsz * Cch * HWsz) return;
    int hw = idx % HWsz;
    int c = (idx / HWsz) % Cch;
    int b = idx / (HWsz * Cch);
    out[idx] = cnb[idx] * xco[(size_t)b * HWsz + hw] + cb[c];
}

extern "C" void kernel_launch(void* const* d_in, const int* in_sizes, int n_in,
                              void* d_out, int out_size, void* d_ws, size_t ws_size,
                              hipStream_t stream) {
    const float* x1      = (const float*)d_in[0];
    const float* x2      = (const float*)d_in[1];
    const float* x3      = (const float*)d_in[2];
    const float* conv1_w = (const float*)d_in[3];
    const float* bn1_g   = (const float*)d_in[4];
    const float* bn1_b   = (const float*)d_in[5];
    const float* conv4_w = (const float*)d_in[6];
    const float* bn4_g   = (const float*)d_in[7];
    const float* bn4_b   = (const float*)d_in[8];
    const float* conv5_w = (const float*)d_in[9];
    const float* bn5_g   = (const float*)d_in[10];
    const float* bn5_b   = (const float*)d_in[11];
    const float* convfs_w= (const float*)d_in[12];
    const float* bnfs_g  = (const float*)d_in[13];
    const float* bnfs_b  = (const float*)d_in[14];
    const float* saq_w   = (const float*)d_in[15];
    const float* saq_b   = (const float*)d_in[16];
    const float* sak_w   = (const float*)d_in[17];
    const float* sak_b   = (const float*)d_in[18];
    const float* sac6_w  = (const float*)d_in[19];
    const float* sac6_b  = (const float*)d_in[20];

    float* ws = (float*)d_ws;
    const size_t TEN = (size_t)Bsz * Cch * HWsz;  // 294912
    float* cat    = ws;                    // B*96*HW = 884736
    float* f1     = cat + (size_t)Bsz * CIN_CAT * HWsz;
    float* f_s_1  = f1 + TEN;
    float* fg     = f_s_1 + TEN;
    float* fs     = fg + TEN;
    float* sfs    = fs + TEN;
    float* fgl    = sfs + TEN;
    float* t1     = fgl + TEN;
    float* qbuf   = t1 + TEN;
    float* kT     = qbuf + TEN;
    float* cnb    = kT + TEN;
    float* logits = cnb + TEN;             // 9216
    float* xco    = logits + BHW;          // 9216
    float* pmax   = xco + BHW;             // 16*9216
    float* ksum   = pmax + (size_t)NSPLIT * BHW;  // 32
    bf16_t* qhi   = (bf16_t*)(ksum + 64);  // 294912 bf16 each
    bf16_t* qlo   = qhi + TEN;
    bf16_t* khi   = qlo + TEN;
    bf16_t* klo   = khi + TEN;

    const int TPB = 256;
    const int GRID_TEN = (int)((TEN + TPB - 1) / TPB);   // 1152
    const int GRID_CONV = Bsz * 18;                       // 72 tiles (3x, 6y, 4b)

    // 1. f3 = resize(x3, 192->48) into cat ch[0:32)
    resize_kernel<<<GRID_TEN, TPB, 0, stream>>>(x3, cat, 192, 192, 192, 192 * 192, 0,
                                                191.0f / 47.0f, 191.0f / 47.0f, CIN_CAT, 0);
    // 2. f2 = resize(x2, 96->48) into cat ch[32:64)
    resize_kernel<<<GRID_TEN, TPB, 0, stream>>>(x2, cat, 96, 96, 96, 96 * 96, 0,
                                                95.0f / 47.0f, 95.0f / 47.0f, CIN_CAT, 32);
    // 3. x1 into cat ch[64:96)
    copy_x1_kernel<<<GRID_TEN, TPB, 0, stream>>>(x1, cat);
    // 4. f1 = bn1(conv1(cat))
    conv3x3_tile<CIN_CAT, Cch, 2, false, false><<<GRID_CONV, 256, 0, stream>>>(
        cat, nullptr, conv1_w, bn1_g, bn1_b, nullptr, f1);
    // 5. f_s_1 = resize(f1[:, :, 32:48, 32:48], 16->48)  (chunk idx is always 8)
    resize_kernel<<<GRID_TEN, TPB, 0, stream>>>(f1, f_s_1, 16, 16, Ww, HWsz, 32 * Ww + 32,
                                                15.0f / 47.0f, 15.0f / 47.0f, Cch, 0);

    // SA macro: x -> out
    auto run_sa = [&](const float* xin, float* outp) {
        dim3 g1((BHW + TPB - 1) / TPB, 3);
        qkc_kernel<<<g1, TPB, 0, stream>>>(xin, saq_w, saq_b, sak_w, sak_b, sac6_w,
                                           qbuf, kT, cnb, qhi, qlo, khi, klo);
        ksum_kernel<<<Cch, 256, 0, stream>>>(kT, ksum);
        dim3 g2(144, NSPLIT);
        score_mfma_kernel<<<g2, 256, 0, stream>>>(qhi, qlo, khi, klo, pmax);
        logits_kernel<<<BHW / 256, 256, 0, stream>>>(qbuf, ksum, pmax, logits);
        softmax_kernel<<<Bsz, 256, 0, stream>>>(logits, xco);
        sa_apply_kernel<<<GRID_TEN, TPB, 0, stream>>>(cnb, xco, sac6_b, outp);
    };

    // 6-8. fg = sa(f1); fs = sa(f_s_1); sfs = sa(fs)
    run_sa(f1, fg);
    run_sa(f_s_1, fs);
    run_sa(fs, sfs);

    // 9. fgl = bnfs(convfs(fg + sfs))
    conv3x3_tile<Cch, Cch, 2, true, false><<<GRID_CONV, 256, 0, stream>>>(
        fg, sfs, convfs_w, bnfs_g, bnfs_b, nullptr, fgl);
    // 10. t1 = bn4(conv4(fgl)) + fg
    conv3x3_tile<Cch, Cch, 2, false, true><<<GRID_CONV, 256, 0, stream>>>(
        fgl, nullptr, conv4_w, bn4_g, bn4_b, fg, t1);
    // 11. out = bn5(conv5(t1))   (B,1,48,48)
    conv3x3_tile<Cch, 1, 1, false, false><<<GRID_CONV, 128, 0, stream>>>(
        t1, nullptr, conv5_w, bn5_g, bn5_b, nullptr, (float*)d_out);
}

// Round 11
// 440.338 us; speedup vs baseline: 2.3126x; 2.0774x over previous
//
#include <hip/hip_runtime.h>
#include <math.h>

#define Bsz 4
#define Cch 32
#define Hh 48
#define Ww 48
#define HWsz 2304          // 48*48
#define BHW 9216           // 4*2304
#define CIN_CAT 96
#define NSPLIT 16          // column splits for max partials (4 per b-group)
#define TILES_PER_SPLIT 36 // 576 col-tiles / 16

typedef __bf16 bf16_t;
typedef __bf16 bf16x8 __attribute__((ext_vector_type(8)));
typedef float f32x4 __attribute__((ext_vector_type(4)));

// ---------------- bilinear resize, align_corners=True ----------------
__global__ void resize_kernel(const float* __restrict__ in, float* __restrict__ out,
                              int inH, int inW, int rowStride, int chanStride, int baseOff,
                              float scaleY, float scaleX, int outCtot, int chanOff) {
    int idx = blockIdx.x * blockDim.x + threadIdx.x;
    if (idx >= Bsz * Cch * HWsz) return;
    int x = idx % Ww;
    int y = (idx / Ww) % Hh;
    int c = (idx / HWsz) % Cch;
    int b = idx / (HWsz * Cch);
    float fy = y * scaleY;
    float fx = x * scaleX;
    int y0 = (int)floorf(fy); int x0 = (int)floorf(fx);
    y0 = min(y0, inH - 1); x0 = min(x0, inW - 1);
    int y1 = min(y0 + 1, inH - 1); int x1 = min(x0 + 1, inW - 1);
    float wy = fy - (float)y0, wx = fx - (float)x0;
    const float* src = in + (size_t)(b * Cch + c) * chanStride + baseOff;
    float v00 = src[y0 * rowStride + x0];
    float v01 = src[y0 * rowStride + x1];
    float v10 = src[y1 * rowStride + x0];
    float v11 = src[y1 * rowStride + x1];
    float top = v00 * (1.f - wx) + v01 * wx;
    float bot = v10 * (1.f - wx) + v11 * wx;
    float r = top * (1.f - wy) + bot * wy;
    out[((size_t)(b * outCtot) + c + chanOff) * HWsz + y * Ww + x] = r;
}

// copy x1 (B,32,HW) into cat channels [64..96)
__global__ void copy_x1_kernel(const float* __restrict__ x1, float* __restrict__ cat) {
    int idx = blockIdx.x * blockDim.x + threadIdx.x;
    if (idx >= Bsz * Cch * HWsz) return;
    int hw = idx % HWsz;
    int c = (idx / HWsz) % Cch;
    int b = idx / (HWsz * Cch);
    cat[((size_t)(b * CIN_CAT) + 64 + c) * HWsz + hw] = x1[idx];
}

// ---------------- conv prep: activations [b][ci][hw] -> [p][ci] split-bf16 --------
__global__ void prep_x_kernel(const float* __restrict__ X, const float* __restrict__ X2,
                              int CINr, bf16_t* __restrict__ xhi, bf16_t* __restrict__ xlo) {
    int idx = blockIdx.x * 256 + threadIdx.x;
    if (idx >= BHW * CINr) return;
    int ci = idx % CINr;
    int p = idx / CINr;
    int b = p / HWsz;
    int hw = p % HWsz;
    size_t gi = ((size_t)(b * CINr) + ci) * HWsz + hw;
    float v = X[gi];
    if (X2) v += X2[gi];
    bf16_t h = (bf16_t)v;
    xhi[idx] = h;
    xlo[idx] = (bf16_t)(v - (float)h);
}

// ---------------- conv prep: weights [co][ci][3][3] -> [tap][co32][ci] split-bf16 --
__global__ void prep_w_kernel(const float* __restrict__ w, int Cout, int CINr,
                              bf16_t* __restrict__ whi, bf16_t* __restrict__ wlo) {
    int idx = blockIdx.x * 256 + threadIdx.x;
    if (idx >= 9 * 32 * CINr) return;
    int ci = idx % CINr;
    int rem = idx / CINr;
    int co = rem % 32;
    int tap = rem / 32;
    float v = (co < Cout) ? w[((size_t)(co * CINr) + ci) * 9 + tap] : 0.f;
    bf16_t h = (bf16_t)v;
    whi[idx] = h;
    wlo[idx] = (bf16_t)(v - (float)h);
}

__global__ void zeros_kernel(bf16_t* __restrict__ zbuf) {
    if (threadIdx.x < 128) zbuf[threadIdx.x] = (bf16_t)0.f;
}

// ---------------- 3x3 conv as implicit GEMM on MFMA, fused BN (+residual) ---------
// wave = one 16-pixel M-tile x 32 co (two 16x16 tiles). 9 taps x CIN/32 chunks x
// 3 split-bf16 MFMAs per tile. Boundary taps read a zeros row.
// grid 144 x 256 threads (576 waves).
template<int CIN, int COUT_WRITE, bool HASRES>
__global__ __launch_bounds__(256) void conv_mfma_kernel(
        const bf16_t* __restrict__ xhi, const bf16_t* __restrict__ xlo,
        const bf16_t* __restrict__ whi, const bf16_t* __restrict__ wlo,
        const bf16_t* __restrict__ zbuf,
        const float* __restrict__ bng, const float* __restrict__ bnb,
        const float* __restrict__ res, float* __restrict__ out) {
    int lane = threadIdx.x & 63;
    int mt = blockIdx.x * 4 + (threadIdx.x >> 6);   // 0..575
    int lrow = lane & 15;
    int lk = lane >> 4;
    int p = mt * 16 + lrow;
    int hw = p % HWsz;
    int y = hw / Ww, x = hw % Ww;
    f32x4 acc0 = {0.f, 0.f, 0.f, 0.f};
    f32x4 acc1 = {0.f, 0.f, 0.f, 0.f};
#pragma unroll
    for (int tap = 0; tap < 9; ++tap) {
        const int dy = tap / 3 - 1, dx = tap % 3 - 1;
        bool valid = ((unsigned)(y + dy) < (unsigned)Hh) && ((unsigned)(x + dx) < (unsigned)Ww);
        const bf16_t* ah = valid ? xhi + (size_t)(p + dy * Ww + dx) * CIN : zbuf;
        const bf16_t* al = valid ? xlo + (size_t)(p + dy * Ww + dx) * CIN : zbuf;
#pragma unroll
        for (int c = 0; c < CIN / 32; ++c) {
            bf16x8 ahi = *(const bf16x8*)(ah + c * 32 + lk * 8);
            bf16x8 alo = *(const bf16x8*)(al + c * 32 + lk * 8);
            size_t w0 = (size_t)(tap * 32 + lrow) * CIN + c * 32 + lk * 8;
            size_t w1 = (size_t)(tap * 32 + 16 + lrow) * CIN + c * 32 + lk * 8;
            bf16x8 bhi0 = *(const bf16x8*)(whi + w0);
            bf16x8 blo0 = *(const bf16x8*)(wlo + w0);
            bf16x8 bhi1 = *(const bf16x8*)(whi + w1);
            bf16x8 blo1 = *(const bf16x8*)(wlo + w1);
            acc0 = __builtin_amdgcn_mfma_f32_16x16x32_bf16(ahi, bhi0, acc0, 0, 0, 0);
            acc0 = __builtin_amdgcn_mfma_f32_16x16x32_bf16(ahi, blo0, acc0, 0, 0, 0);
            acc0 = __builtin_amdgcn_mfma_f32_16x16x32_bf16(alo, bhi0, acc0, 0, 0, 0);
            acc1 = __builtin_amdgcn_mfma_f32_16x16x32_bf16(ahi, bhi1, acc1, 0, 0, 0);
            acc1 = __builtin_amdgcn_mfma_f32_16x16x32_bf16(ahi, blo1, acc1, 0, 0, 0);
            acc1 = __builtin_amdgcn_mfma_f32_16x16x32_bf16(alo, bhi1, acc1, 0, 0, 0);
        }
    }
    float bsc = rsqrtf(1.0f + 1e-5f);
    int co0 = lrow, co1 = 16 + lrow;
    float s0, b0, s1 = 0.f, b1 = 0.f;
    if (COUT_WRITE == 32) {
        s0 = bng[co0] * bsc; b0 = bnb[co0];
        s1 = bng[co1] * bsc; b1 = bnb[co1];
    } else {
        s0 = bng[0] * bsc; b0 = bnb[0];
    }
    // C/D layout: col = lane&15 (= co within tile), row = (lane>>4)*4 + r (= pixel)
#pragma unroll
    for (int r = 0; r < 4; ++r) {
        int pr = mt * 16 + lk * 4 + r;
        int br = pr / HWsz, hwr = pr % HWsz;
        if (COUT_WRITE == 32) {
            size_t o0 = ((size_t)(br * 32) + co0) * HWsz + hwr;
            float v0 = acc0[r] * s0 + b0;
            if (HASRES) v0 += res[o0];
            out[o0] = v0;
            size_t o1 = ((size_t)(br * 32) + co1) * HWsz + hwr;
            float v1 = acc1[r] * s1 + b1;
            if (HASRES) v1 += res[o1];
            out[o1] = v1;
        } else {
            if (lrow == 0) out[(size_t)br * HWsz + hwr] = acc0[r] * s0 + b0;
        }
    }
}

// ---------------- SA: fused 1x1 convs for q, k, c(no-bias) ----------------
__global__ void qkc_kernel(const float* __restrict__ x,
                           const float* __restrict__ qw, const float* __restrict__ qb,
                           const float* __restrict__ kw, const float* __restrict__ kb,
                           const float* __restrict__ cw,
                           float* __restrict__ qbuf, float* __restrict__ kT,
                           float* __restrict__ cnb,
                           bf16_t* __restrict__ qhi, bf16_t* __restrict__ qlo,
                           bf16_t* __restrict__ khi, bf16_t* __restrict__ klo) {
    int p = blockIdx.x * blockDim.x + threadIdx.x;  // pixel 0..9215
    if (p >= BHW) return;
    int b = p / HWsz;
    int hw = p % HWsz;
    float xin[Cch];
#pragma unroll
    for (int ci = 0; ci < Cch; ++ci) xin[ci] = x[((size_t)(b * Cch) + ci) * HWsz + hw];
    int which = blockIdx.y;
    if (which == 0) {
        for (int co = 0; co < Cch; ++co) {
            float acc = qb[co];
#pragma unroll
            for (int ci = 0; ci < Cch; ++ci) acc += xin[ci] * qw[co * Cch + ci];
            size_t f = ((size_t)(b * Cch) + co) * HWsz + hw;
            qbuf[f] = acc;
            bf16_t h = (bf16_t)acc;
            qhi[f] = h;
            qlo[f] = (bf16_t)(acc - (float)h);
        }
    } else if (which == 1) {
        for (int co = 0; co < Cch; ++co) {
            float acc = kb[co];
#pragma unroll
            for (int ci = 0; ci < Cch; ++ci) acc += xin[ci] * kw[co * Cch + ci];
            size_t f = (size_t)p * Cch + co;
            kT[f] = acc;
            bf16_t h = (bf16_t)acc;
            khi[f] = h;
            klo[f] = (bf16_t)(acc - (float)h);
        }
    } else {
        for (int co = 0; co < Cch; ++co) {
            float acc = 0.f;
#pragma unroll
            for (int ci = 0; ci < Cch; ++ci) acc += xin[ci] * cw[co * Cch + ci];
            cnb[((size_t)(b * Cch) + co) * HWsz + hw] = acc;
        }
    }
}

// ---------------- ksum: column sums of kT (exact fp32, for the mean term) ----------
__global__ void ksum_kernel(const float* __restrict__ kT, float* __restrict__ ksum) {
    int c = blockIdx.x;   // 0..31
    int tid = threadIdx.x;
    __shared__ float red[256];
    float s = 0.f;
    for (int j = tid; j < BHW; j += 256) s += kT[(size_t)j * Cch + c];
    red[tid] = s; __syncthreads();
    for (int st = 128; st > 0; st >>= 1) { if (tid < st) red[tid] += red[tid + st]; __syncthreads(); }
    if (tid == 0) ksum[c] = red[0];
}

// ---------------- score max-scan via MFMA (split-bf16: hi*hi + hi*lo + lo*hi) -------
__global__ void score_mfma_kernel(const bf16_t* __restrict__ qhi, const bf16_t* __restrict__ qlo,
                                  const bf16_t* __restrict__ khi, const bf16_t* __restrict__ klo,
                                  float* __restrict__ pmax) {
    int wave = threadIdx.x >> 6;
    int lane = threadIdx.x & 63;
    int rt = blockIdx.x * 4 + wave;   // 0..575
    int cs = blockIdx.y;              // 0..15
    int lrow = lane & 15;
    int lk = lane >> 4;
    size_t aoff = (size_t)(rt * 16 + lrow) * Cch + lk * 8;
    bf16x8 ahi = *(const bf16x8*)(qhi + aoff);
    bf16x8 alo = *(const bf16x8*)(qlo + aoff);
    f32x4 mx = {-1e30f, -1e30f, -1e30f, -1e30f};
    int ct0 = cs * TILES_PER_SPLIT;
    for (int ct = ct0; ct < ct0 + TILES_PER_SPLIT; ++ct) {
        size_t boff = (size_t)(ct * 16 + lrow) * Cch + lk * 8;
        bf16x8 bhi = *(const bf16x8*)(khi + boff);
        bf16x8 blo = *(const bf16x8*)(klo + boff);
        f32x4 d = {0.f, 0.f, 0.f, 0.f};
        d = __builtin_amdgcn_mfma_f32_16x16x32_bf16(ahi, bhi, d, 0, 0, 0);
        d = __builtin_amdgcn_mfma_f32_16x16x32_bf16(ahi, blo, d, 0, 0, 0);
        d = __builtin_amdgcn_mfma_f32_16x16x32_bf16(alo, bhi, d, 0, 0, 0);
#pragma unroll
        for (int r = 0; r < 4; ++r) mx[r] = fmaxf(mx[r], d[r]);
    }
#pragma unroll
    for (int off = 1; off < 16; off <<= 1) {
#pragma unroll
        for (int r = 0; r < 4; ++r) {
            float o = __shfl_xor(mx[r], off, 64);
            mx[r] = fmaxf(mx[r], o);
        }
    }
    if (lrow == 0) {
#pragma unroll
        for (int r = 0; r < 4; ++r) {
            int row = rt * 16 + lk * 4 + r;   // C/D layout: row=(lane>>4)*4+reg
            pmax[(size_t)cs * BHW + row] = mx[r];
        }
    }
}

// ---------------- logits: mean_b(max) + q.ksum/BHW, scaled ----------------
__global__ void logits_kernel(const float* __restrict__ qbuf, const float* __restrict__ ksum,
                              const float* __restrict__ pmax, float* __restrict__ logits) {
    __shared__ float ks[Cch];
    if (threadIdx.x < Cch) ks[threadIdx.x] = ksum[threadIdx.x];
    __syncthreads();
    int i = blockIdx.x * 256 + threadIdx.x;
    if (i >= BHW) return;
    float msum = 0.f;
#pragma unroll
    for (int b = 0; b < 4; ++b) {
        float m = -1e30f;
#pragma unroll
        for (int k = 0; k < 4; ++k) m = fmaxf(m, pmax[(size_t)(b * 4 + k) * BHW + i]);
        msum += m;
    }
    float dot = 0.f;
    const float4* qp = (const float4*)(qbuf + (size_t)i * Cch);
#pragma unroll
    for (int t = 0; t < 8; ++t) {
        float4 v = qp[t];
        dot += v.x * ks[4 * t] + v.y * ks[4 * t + 1] + v.z * ks[4 * t + 2] + v.w * ks[4 * t + 3];
    }
    logits[i] = (msum * 0.25f + dot * (1.0f / (float)BHW)) * 0.17677669529663687f;
}

// softmax over HW per b -> xco
__global__ void softmax_kernel(const float* __restrict__ logits, float* __restrict__ xco) {
    int b = blockIdx.x;
    int tid = threadIdx.x;
    __shared__ float red[256];
    const float* l = logits + (size_t)b * HWsz;
    float m = -1e30f;
    for (int h = tid; h < HWsz; h += 256) m = fmaxf(m, l[h]);
    red[tid] = m; __syncthreads();
    for (int s = 128; s > 0; s >>= 1) { if (tid < s) red[tid] = fmaxf(red[tid], red[tid + s]); __syncthreads(); }
    m = red[0]; __syncthreads();
    float s = 0.f;
    for (int h = tid; h < HWsz; h += 256) s += expf(l[h] - m);
    red[tid] = s; __syncthreads();
    for (int st = 128; st > 0; st >>= 1) { if (tid < st) red[tid] += red[tid + st]; __syncthreads(); }
    float inv = 1.0f / red[0];
    for (int h = tid; h < HWsz; h += 256) xco[(size_t)b * HWsz + h] = expf(l[h] - m) * inv;
}

// out[b,c,hw] = cnb[b,c,hw] * xco[b,hw] + cb[c]
__global__ void sa_apply_kernel(const float* __restrict__ cnb, const float* __restrict__ xco,
                                const float* __restrict__ cb, float* __restrict__ out) {
    int idx = blockIdx.x * blockDim.x + threadIdx.x;
    if (idx >= Bsz * Cch * HWsz) return;
    int hw = idx % HWsz;
    int c = (idx / HWsz) % Cch;
    int b = idx / (HWsz * Cch);
    out[idx] = cnb[idx] * xco[(size_t)b * HWsz + hw] + cb[c];
}

extern "C" void kernel_launch(void* const* d_in, const int* in_sizes, int n_in,
                              void* d_out, int out_size, void* d_ws, size_t ws_size,
                              hipStream_t stream) {
    const float* x1      = (const float*)d_in[0];
    const float* x2      = (const float*)d_in[1];
    const float* x3      = (const float*)d_in[2];
    const float* conv1_w = (const float*)d_in[3];
    const float* bn1_g   = (const float*)d_in[4];
    const float* bn1_b   = (const float*)d_in[5];
    const float* conv4_w = (const float*)d_in[6];
    const float* bn4_g   = (const float*)d_in[7];
    const float* bn4_b   = (const float*)d_in[8];
    const float* conv5_w = (const float*)d_in[9];
    const float* bn5_g   = (const float*)d_in[10];
    const float* bn5_b   = (const float*)d_in[11];
    const float* convfs_w= (const float*)d_in[12];
    const float* bnfs_g  = (const float*)d_in[13];
    const float* bnfs_b  = (const float*)d_in[14];
    const float* saq_w   = (const float*)d_in[15];
    const float* saq_b   = (const float*)d_in[16];
    const float* sak_w   = (const float*)d_in[17];
    const float* sak_b   = (const float*)d_in[18];
    const float* sac6_w  = (const float*)d_in[19];
    const float* sac6_b  = (const float*)d_in[20];

    float* ws = (float*)d_ws;
    const size_t TEN = (size_t)Bsz * Cch * HWsz;  // 294912
    // ---- persistent region (~11.9 MB) ----
    float* cat    = ws;                            // B*96*HW
    float* f1     = cat + (size_t)Bsz * CIN_CAT * HWsz;
    float* f_s_1  = f1 + TEN;
    float* fg     = f_s_1 + TEN;
    float* fs     = fg + TEN;
    float* sfs    = fs + TEN;
    float* fgl    = sfs + TEN;
    float* t1     = fgl + TEN;
    float* logits = t1 + TEN;              // 9216
    float* xco    = logits + BHW;          // 9216
    float* ksum   = xco + BHW;             // 64 floats reserved
    // ---- shared arena: SA-scratch and conv-scratch never live simultaneously ----
    float* arena  = ksum + 64;
    // SA view (live only inside run_sa): 3*TEN f32 + 16*BHW f32 + 4*TEN bf16 ≈ 6.5 MB
    float* qbuf   = arena;
    float* kT     = qbuf + TEN;
    float* cnb    = kT + TEN;
    float* pmax   = cnb + TEN;                       // 16*9216
    bf16_t* qhi   = (bf16_t*)(pmax + (size_t)NSPLIT * BHW);
    bf16_t* qlo   = qhi + TEN;
    bf16_t* khi   = qlo + TEN;
    bf16_t* klo   = khi + TEN;
    // conv view (live only around conv calls): ≈ 3.7 MB, aliases the SA view
    bf16_t* xthi  = (bf16_t*)arena;                  // BHW*96
    bf16_t* xtlo  = xthi + (size_t)BHW * CIN_CAT;
    bf16_t* wthi  = xtlo + (size_t)BHW * CIN_CAT;    // 9*32*96
    bf16_t* wtlo  = wthi + 9 * 32 * CIN_CAT;
    bf16_t* zbuf  = wtlo + 9 * 32 * CIN_CAT;         // 128 zeros

    const int TPB = 256;
    const int GRID_TEN = (int)((TEN + TPB - 1) / TPB);   // 1152
    const int GRID_MFMA = 144;                            // 576 waves

    // 1. f3 = resize(x3, 192->48) into cat ch[0:32)
    resize_kernel<<<GRID_TEN, TPB, 0, stream>>>(x3, cat, 192, 192, 192, 192 * 192, 0,
                                                191.0f / 47.0f, 191.0f / 47.0f, CIN_CAT, 0);
    // 2. f2 = resize(x2, 96->48) into cat ch[32:64)
    resize_kernel<<<GRID_TEN, TPB, 0, stream>>>(x2, cat, 96, 96, 96, 96 * 96, 0,
                                                95.0f / 47.0f, 95.0f / 47.0f, CIN_CAT, 32);
    // 3. x1 into cat ch[64:96)
    copy_x1_kernel<<<GRID_TEN, TPB, 0, stream>>>(x1, cat);
    zeros_kernel<<<1, 128, 0, stream>>>(zbuf);
    // 4. f1 = bn1(conv1(cat))  via implicit-GEMM MFMA
    prep_w_kernel<<<(9 * 32 * CIN_CAT + 255) / 256, 256, 0, stream>>>(conv1_w, 32, CIN_CAT, wthi, wtlo);
    prep_x_kernel<<<(BHW * CIN_CAT + 255) / 256, 256, 0, stream>>>(cat, nullptr, CIN_CAT, xthi, xtlo);
    conv_mfma_kernel<CIN_CAT, 32, false><<<GRID_MFMA, 256, 0, stream>>>(
        xthi, xtlo, wthi, wtlo, zbuf, bn1_g, bn1_b, nullptr, f1);
    // 5. f_s_1 = resize(f1[:, :, 32:48, 32:48], 16->48)  (chunk idx is always 8)
    resize_kernel<<<GRID_TEN, TPB, 0, stream>>>(f1, f_s_1, 16, 16, Ww, HWsz, 32 * Ww + 32,
                                                15.0f / 47.0f, 15.0f / 47.0f, Cch, 0);

    // SA macro: x -> out
    auto run_sa = [&](const float* xin, float* outp) {
        dim3 g1((BHW + TPB - 1) / TPB, 3);
        qkc_kernel<<<g1, TPB, 0, stream>>>(xin, saq_w, saq_b, sak_w, sak_b, sac6_w,
                                           qbuf, kT, cnb, qhi, qlo, khi, klo);
        ksum_kernel<<<Cch, 256, 0, stream>>>(kT, ksum);
        dim3 g2(144, NSPLIT);
        score_mfma_kernel<<<g2, 256, 0, stream>>>(qhi, qlo, khi, klo, pmax);
        logits_kernel<<<BHW / 256, 256, 0, stream>>>(qbuf, ksum, pmax, logits);
        softmax_kernel<<<Bsz, 256, 0, stream>>>(logits, xco);
        sa_apply_kernel<<<GRID_TEN, TPB, 0, stream>>>(cnb, xco, sac6_b, outp);
    };

    // 6-8. fg = sa(f1); fs = sa(f_s_1); sfs = sa(fs)
    run_sa(f1, fg);
    run_sa(f_s_1, fs);
    run_sa(fs, sfs);

    // 9. fgl = bnfs(convfs(fg + sfs))
    zeros_kernel<<<1, 128, 0, stream>>>(zbuf);
    prep_w_kernel<<<(9 * 32 * Cch + 255) / 256, 256, 0, stream>>>(convfs_w, 32, Cch, wthi, wtlo);
    prep_x_kernel<<<(BHW * Cch + 255) / 256, 256, 0, stream>>>(fg, sfs, Cch, xthi, xtlo);
    conv_mfma_kernel<Cch, 32, false><<<GRID_MFMA, 256, 0, stream>>>(
        xthi, xtlo, wthi, wtlo, zbuf, bnfs_g, bnfs_b, nullptr, fgl);
    // 10. t1 = bn4(conv4(fgl)) + fg
    prep_w_kernel<<<(9 * 32 * Cch + 255) / 256, 256, 0, stream>>>(conv4_w, 32, Cch, wthi, wtlo);
    prep_x_kernel<<<(BHW * Cch + 255) / 256, 256, 0, stream>>>(fgl, nullptr, Cch, xthi, xtlo);
    conv_mfma_kernel<Cch, 32, true><<<GRID_MFMA, 256, 0, stream>>>(
        xthi, xtlo, wthi, wtlo, zbuf, bn4_g, bn4_b, fg, t1);
    // 11. out = bn5(conv5(t1))   (B,1,48,48)
    prep_w_kernel<<<(9 * 32 * Cch + 255) / 256, 256, 0, stream>>>(conv5_w, 1, Cch, wthi, wtlo);
    prep_x_kernel<<<(BHW * Cch + 255) / 256, 256, 0, stream>>>(t1, nullptr, Cch, xthi, xtlo);
    conv_mfma_kernel<Cch, 1, false><<<GRID_MFMA, 256, 0, stream>>>(
        xthi, xtlo, wthi, wtlo, zbuf, bn5_g, bn5_b, nullptr, (float*)d_out);
}

// Round 12
// 367.738 us; speedup vs baseline: 2.7692x; 1.1974x over previous
//
#include <hip/hip_runtime.h>
#include <math.h>

#define Bsz 4
#define Cch 32
#define Hh 48
#define Ww 48
#define HWsz 2304          // 48*48
#define BHW 9216           // 4*2304
#define CIN_CAT 96
#define NSPLIT 32          // column splits for max partials (8 per b-group)
#define TILES_PER_SPLIT 18 // 576 col-tiles / 32 (18 | 144 -> split stays in one b)

typedef __bf16 bf16_t;
typedef __bf16 bf16x8 __attribute__((ext_vector_type(8)));
typedef float f32x4 __attribute__((ext_vector_type(4)));

// ---------------- bilinear resize, align_corners=True ----------------
__global__ void resize_kernel(const float* __restrict__ in, float* __restrict__ out,
                              int inH, int inW, int rowStride, int chanStride, int baseOff,
                              float scaleY, float scaleX, int outCtot, int chanOff) {
    int idx = blockIdx.x * blockDim.x + threadIdx.x;
    if (idx >= Bsz * Cch * HWsz) return;
    int x = idx % Ww;
    int y = (idx / Ww) % Hh;
    int c = (idx / HWsz) % Cch;
    int b = idx / (HWsz * Cch);
    float fy = y * scaleY;
    float fx = x * scaleX;
    int y0 = (int)floorf(fy); int x0 = (int)floorf(fx);
    y0 = min(y0, inH - 1); x0 = min(x0, inW - 1);
    int y1 = min(y0 + 1, inH - 1); int x1 = min(x0 + 1, inW - 1);
    float wy = fy - (float)y0, wx = fx - (float)x0;
    const float* src = in + (size_t)(b * Cch + c) * chanStride + baseOff;
    float v00 = src[y0 * rowStride + x0];
    float v01 = src[y0 * rowStride + x1];
    float v10 = src[y1 * rowStride + x0];
    float v11 = src[y1 * rowStride + x1];
    float top = v00 * (1.f - wx) + v01 * wx;
    float bot = v10 * (1.f - wx) + v11 * wx;
    float r = top * (1.f - wy) + bot * wy;
    out[((size_t)(b * outCtot) + c + chanOff) * HWsz + y * Ww + x] = r;
}

// copy x1 (B,32,HW) into cat channels [64..96)
__global__ void copy_x1_kernel(const float* __restrict__ x1, float* __restrict__ cat) {
    int idx = blockIdx.x * blockDim.x + threadIdx.x;
    if (idx >= Bsz * Cch * HWsz) return;
    int hw = idx % HWsz;
    int c = (idx / HWsz) % Cch;
    int b = idx / (HWsz * Cch);
    cat[((size_t)(b * CIN_CAT) + 64 + c) * HWsz + hw] = x1[idx];
}

// ---------------- conv prep: activations [b][ci][hw] -> [p][ci] split-bf16 --------
__global__ void prep_x_kernel(const float* __restrict__ X, const float* __restrict__ X2,
                              int CINr, bf16_t* __restrict__ xhi, bf16_t* __restrict__ xlo) {
    int idx = blockIdx.x * 256 + threadIdx.x;
    if (idx >= BHW * CINr) return;
    int ci = idx % CINr;
    int p = idx / CINr;
    int b = p / HWsz;
    int hw = p % HWsz;
    size_t gi = ((size_t)(b * CINr) + ci) * HWsz + hw;
    float v = X[gi];
    if (X2) v += X2[gi];
    bf16_t h = (bf16_t)v;
    xhi[idx] = h;
    xlo[idx] = (bf16_t)(v - (float)h);
}

// ---------------- conv prep: weights [co][ci][3][3] -> [tap][co32][ci] split-bf16 --
__global__ void prep_w_kernel(const float* __restrict__ w, int Cout, int CINr,
                              bf16_t* __restrict__ whi, bf16_t* __restrict__ wlo) {
    int idx = blockIdx.x * 256 + threadIdx.x;
    if (idx >= 9 * 32 * CINr) return;
    int ci = idx % CINr;
    int rem = idx / CINr;
    int co = rem % 32;
    int tap = rem / 32;
    float v = (co < Cout) ? w[((size_t)(co * CINr) + ci) * 9 + tap] : 0.f;
    bf16_t h = (bf16_t)v;
    whi[idx] = h;
    wlo[idx] = (bf16_t)(v - (float)h);
}

__global__ void zeros_kernel(bf16_t* __restrict__ zbuf) {
    if (threadIdx.x < 128) zbuf[threadIdx.x] = (bf16_t)0.f;
}

// ---------------- 3x3 conv as implicit GEMM on MFMA, fused BN (+residual) ---------
// wave = one 16-pixel M-tile x 32 co (two 16x16 tiles). 9 taps x CIN/32 chunks x
// 3 split-bf16 MFMAs per tile. Boundary taps read a zeros row.
// grid 144 x 256 threads (576 waves).
template<int CIN, int COUT_WRITE, bool HASRES>
__global__ __launch_bounds__(256) void conv_mfma_kernel(
        const bf16_t* __restrict__ xhi, const bf16_t* __restrict__ xlo,
        const bf16_t* __restrict__ whi, const bf16_t* __restrict__ wlo,
        const bf16_t* __restrict__ zbuf,
        const float* __restrict__ bng, const float* __restrict__ bnb,
        const float* __restrict__ res, float* __restrict__ out) {
    int lane = threadIdx.x & 63;
    int mt = blockIdx.x * 4 + (threadIdx.x >> 6);   // 0..575
    int lrow = lane & 15;
    int lk = lane >> 4;
    int p = mt * 16 + lrow;
    int hw = p % HWsz;
    int y = hw / Ww, x = hw % Ww;
    f32x4 acc0 = {0.f, 0.f, 0.f, 0.f};
    f32x4 acc1 = {0.f, 0.f, 0.f, 0.f};
#pragma unroll
    for (int tap = 0; tap < 9; ++tap) {
        const int dy = tap / 3 - 1, dx = tap % 3 - 1;
        bool valid = ((unsigned)(y + dy) < (unsigned)Hh) && ((unsigned)(x + dx) < (unsigned)Ww);
        const bf16_t* ah = valid ? xhi + (size_t)(p + dy * Ww + dx) * CIN : zbuf;
        const bf16_t* al = valid ? xlo + (size_t)(p + dy * Ww + dx) * CIN : zbuf;
#pragma unroll
        for (int c = 0; c < CIN / 32; ++c) {
            bf16x8 ahi = *(const bf16x8*)(ah + c * 32 + lk * 8);
            bf16x8 alo = *(const bf16x8*)(al + c * 32 + lk * 8);
            size_t w0 = (size_t)(tap * 32 + lrow) * CIN + c * 32 + lk * 8;
            size_t w1 = (size_t)(tap * 32 + 16 + lrow) * CIN + c * 32 + lk * 8;
            bf16x8 bhi0 = *(const bf16x8*)(whi + w0);
            bf16x8 blo0 = *(const bf16x8*)(wlo + w0);
            bf16x8 bhi1 = *(const bf16x8*)(whi + w1);
            bf16x8 blo1 = *(const bf16x8*)(wlo + w1);
            acc0 = __builtin_amdgcn_mfma_f32_16x16x32_bf16(ahi, bhi0, acc0, 0, 0, 0);
            acc0 = __builtin_amdgcn_mfma_f32_16x16x32_bf16(ahi, blo0, acc0, 0, 0, 0);
            acc0 = __builtin_amdgcn_mfma_f32_16x16x32_bf16(alo, bhi0, acc0, 0, 0, 0);
            acc1 = __builtin_amdgcn_mfma_f32_16x16x32_bf16(ahi, bhi1, acc1, 0, 0, 0);
            acc1 = __builtin_amdgcn_mfma_f32_16x16x32_bf16(ahi, blo1, acc1, 0, 0, 0);
            acc1 = __builtin_amdgcn_mfma_f32_16x16x32_bf16(alo, bhi1, acc1, 0, 0, 0);
        }
    }
    float bsc = rsqrtf(1.0f + 1e-5f);
    int co0 = lrow, co1 = 16 + lrow;
    float s0, b0, s1 = 0.f, b1 = 0.f;
    if (COUT_WRITE == 32) {
        s0 = bng[co0] * bsc; b0 = bnb[co0];
        s1 = bng[co1] * bsc; b1 = bnb[co1];
    } else {
        s0 = bng[0] * bsc; b0 = bnb[0];
    }
    // C/D layout: col = lane&15 (= co within tile), row = (lane>>4)*4 + r (= pixel)
#pragma unroll
    for (int r = 0; r < 4; ++r) {
        int pr = mt * 16 + lk * 4 + r;
        int br = pr / HWsz, hwr = pr % HWsz;
        if (COUT_WRITE == 32) {
            size_t o0 = ((size_t)(br * 32) + co0) * HWsz + hwr;
            float v0 = acc0[r] * s0 + b0;
            if (HASRES) v0 += res[o0];
            out[o0] = v0;
            size_t o1 = ((size_t)(br * 32) + co1) * HWsz + hwr;
            float v1 = acc1[r] * s1 + b1;
            if (HASRES) v1 += res[o1];
            out[o1] = v1;
        } else {
            if (lrow == 0) out[(size_t)br * HWsz + hwr] = acc0[r] * s0 + b0;
        }
    }
}

// ---------------- SA: fused 1x1 convs for q, k, c(no-bias) ----------------
__global__ void qkc_kernel(const float* __restrict__ x,
                           const float* __restrict__ qw, const float* __restrict__ qb,
                           const float* __restrict__ kw, const float* __restrict__ kb,
                           const float* __restrict__ cw,
                           float* __restrict__ qbuf, float* __restrict__ kT,
                           float* __restrict__ cnb,
                           bf16_t* __restrict__ qhi, bf16_t* __restrict__ qlo,
                           bf16_t* __restrict__ khi, bf16_t* __restrict__ klo) {
    int p = blockIdx.x * blockDim.x + threadIdx.x;  // pixel 0..9215
    if (p >= BHW) return;
    int b = p / HWsz;
    int hw = p % HWsz;
    float xin[Cch];
#pragma unroll
    for (int ci = 0; ci < Cch; ++ci) xin[ci] = x[((size_t)(b * Cch) + ci) * HWsz + hw];
    int which = blockIdx.y;
    if (which == 0) {
        for (int co = 0; co < Cch; ++co) {
            float acc = qb[co];
#pragma unroll
            for (int ci = 0; ci < Cch; ++ci) acc += xin[ci] * qw[co * Cch + ci];
            size_t f = ((size_t)(b * Cch) + co) * HWsz + hw;
            qbuf[f] = acc;
            bf16_t h = (bf16_t)acc;
            qhi[f] = h;
            qlo[f] = (bf16_t)(acc - (float)h);
        }
    } else if (which == 1) {
        for (int co = 0; co < Cch; ++co) {
            float acc = kb[co];
#pragma unroll
            for (int ci = 0; ci < Cch; ++ci) acc += xin[ci] * kw[co * Cch + ci];
            size_t f = (size_t)p * Cch + co;
            kT[f] = acc;
            bf16_t h = (bf16_t)acc;
            khi[f] = h;
            klo[f] = (bf16_t)(acc - (float)h);
        }
    } else {
        for (int co = 0; co < Cch; ++co) {
            float acc = 0.f;
#pragma unroll
            for (int ci = 0; ci < Cch; ++ci) acc += xin[ci] * cw[co * Cch + ci];
            cnb[((size_t)(b * Cch) + co) * HWsz + hw] = acc;
        }
    }
}

// ---------------- ksum: column sums of kT (exact fp32, for the mean term) ----------
__global__ void ksum_kernel(const float* __restrict__ kT, float* __restrict__ ksum) {
    int c = blockIdx.x;   // 0..31
    int tid = threadIdx.x;
    __shared__ float red[256];
    float s = 0.f;
    for (int j = tid; j < BHW; j += 256) s += kT[(size_t)j * Cch + c];
    red[tid] = s; __syncthreads();
    for (int st = 128; st > 0; st >>= 1) { if (tid < st) red[tid] += red[tid + st]; __syncthreads(); }
    if (tid == 0) ksum[c] = red[0];
}

// ---------------- score max-scan via MFMA (split-bf16: hi*hi + hi*lo + lo*hi) -------
// 4 row-tiles per wave: B fragments loaded once feed 4 independent MFMA chains,
// cutting L2 B-traffic 4x (663 MB -> 166 MB). grid (36, NSPLIT) x 256 threads.
__global__ void score_mfma_kernel(const bf16_t* __restrict__ qhi, const bf16_t* __restrict__ qlo,
                                  const bf16_t* __restrict__ khi, const bf16_t* __restrict__ klo,
                                  float* __restrict__ pmax) {
    int wave = threadIdx.x >> 6;
    int lane = threadIdx.x & 63;
    int gw = blockIdx.x * 4 + wave;   // 0..143, owns row-tiles gw*4 .. gw*4+3
    int cs = blockIdx.y;              // 0..31
    int lrow = lane & 15;
    int lk = lane >> 4;
    bf16x8 ahi[4], alo[4];
#pragma unroll
    for (int j = 0; j < 4; ++j) {
        size_t aoff = (size_t)((gw * 4 + j) * 16 + lrow) * Cch + lk * 8;
        ahi[j] = *(const bf16x8*)(qhi + aoff);
        alo[j] = *(const bf16x8*)(qlo + aoff);
    }
    f32x4 mx[4];
#pragma unroll
    for (int j = 0; j < 4; ++j) { mx[j][0] = -1e30f; mx[j][1] = -1e30f; mx[j][2] = -1e30f; mx[j][3] = -1e30f; }
    int ct0 = cs * TILES_PER_SPLIT;
#pragma unroll 2
    for (int ct = ct0; ct < ct0 + TILES_PER_SPLIT; ++ct) {
        size_t boff = (size_t)(ct * 16 + lrow) * Cch + lk * 8;
        bf16x8 bhi = *(const bf16x8*)(khi + boff);
        bf16x8 blo = *(const bf16x8*)(klo + boff);
#pragma unroll
        for (int j = 0; j < 4; ++j) {
            f32x4 d = {0.f, 0.f, 0.f, 0.f};
            d = __builtin_amdgcn_mfma_f32_16x16x32_bf16(ahi[j], bhi, d, 0, 0, 0);
            d = __builtin_amdgcn_mfma_f32_16x16x32_bf16(ahi[j], blo, d, 0, 0, 0);
            d = __builtin_amdgcn_mfma_f32_16x16x32_bf16(alo[j], bhi, d, 0, 0, 0);
#pragma unroll
            for (int r = 0; r < 4; ++r) mx[j][r] = fmaxf(mx[j][r], d[r]);
        }
    }
    // reduce max across the 16 column-lanes of each row group
#pragma unroll
    for (int off = 1; off < 16; off <<= 1) {
#pragma unroll
        for (int j = 0; j < 4; ++j) {
#pragma unroll
            for (int r = 0; r < 4; ++r) {
                float o = __shfl_xor(mx[j][r], off, 64);
                mx[j][r] = fmaxf(mx[j][r], o);
            }
        }
    }
    if (lrow == 0) {
#pragma unroll
        for (int j = 0; j < 4; ++j) {
#pragma unroll
            for (int r = 0; r < 4; ++r) {
                int row = (gw * 4 + j) * 16 + lk * 4 + r;   // C/D layout: row=(lane>>4)*4+reg
                pmax[(size_t)cs * BHW + row] = mx[j][r];
            }
        }
    }
}

// ---------------- logits: mean_b(max) + q.ksum/BHW, scaled ----------------
__global__ void logits_kernel(const float* __restrict__ qbuf, const float* __restrict__ ksum,
                              const float* __restrict__ pmax, float* __restrict__ logits) {
    __shared__ float ks[Cch];
    if (threadIdx.x < Cch) ks[threadIdx.x] = ksum[threadIdx.x];
    __syncthreads();
    int i = blockIdx.x * 256 + threadIdx.x;
    if (i >= BHW) return;
    float msum = 0.f;
#pragma unroll
    for (int b = 0; b < 4; ++b) {
        float m = -1e30f;
#pragma unroll
        for (int k = 0; k < 8; ++k) m = fmaxf(m, pmax[(size_t)(b * 8 + k) * BHW + i]);
        msum += m;
    }
    float dot = 0.f;
    const float4* qp = (const float4*)(qbuf + (size_t)i * Cch);
#pragma unroll
    for (int t = 0; t < 8; ++t) {
        float4 v = qp[t];
        dot += v.x * ks[4 * t] + v.y * ks[4 * t + 1] + v.z * ks[4 * t + 2] + v.w * ks[4 * t + 3];
    }
    logits[i] = (msum * 0.25f + dot * (1.0f / (float)BHW)) * 0.17677669529663687f;
}

// softmax over HW per b -> xco
__global__ void softmax_kernel(const float* __restrict__ logits, float* __restrict__ xco) {
    int b = blockIdx.x;
    int tid = threadIdx.x;
    __shared__ float red[256];
    const float* l = logits + (size_t)b * HWsz;
    float m = -1e30f;
    for (int h = tid; h < HWsz; h += 256) m = fmaxf(m, l[h]);
    red[tid] = m; __syncthreads();
    for (int s = 128; s > 0; s >>= 1) { if (tid < s) red[tid] = fmaxf(red[tid], red[tid + s]); __syncthreads(); }
    m = red[0]; __syncthreads();
    float s = 0.f;
    for (int h = tid; h < HWsz; h += 256) s += expf(l[h] - m);
    red[tid] = s; __syncthreads();
    for (int st = 128; st > 0; st >>= 1) { if (tid < st) red[tid] += red[tid + st]; __syncthreads(); }
    float inv = 1.0f / red[0];
    for (int h = tid; h < HWsz; h += 256) xco[(size_t)b * HWsz + h] = expf(l[h] - m) * inv;
}

// out[b,c,hw] = cnb[b,c,hw] * xco[b,hw] + cb[c]
__global__ void sa_apply_kernel(const float* __restrict__ cnb, const float* __restrict__ xco,
                                const float* __restrict__ cb, float* __restrict__ out) {
    int idx = blockIdx.x * blockDim.x + threadIdx.x;
    if (idx >= Bsz * Cch * HWsz) return;
    int hw = idx % HWsz;
    int c = (idx / HWsz) % Cch;
    int b = idx / (HWsz * Cch);
    out[idx] = cnb[idx] * xco[(size_t)b * HWsz + hw] + cb[c];
}

extern "C" void kernel_launch(void* const* d_in, const int* in_sizes, int n_in,
                              void* d_out, int out_size, void* d_ws, size_t ws_size,
                              hipStream_t stream) {
    const float* x1      = (const float*)d_in[0];
    const float* x2      = (const float*)d_in[1];
    const float* x3      = (const float*)d_in[2];
    const float* conv1_w = (const float*)d_in[3];
    const float* bn1_g   = (const float*)d_in[4];
    const float* bn1_b   = (const float*)d_in[5];
    const float* conv4_w = (const float*)d_in[6];
    const float* bn4_g   = (const float*)d_in[7];
    const float* bn4_b   = (const float*)d_in[8];
    const float* conv5_w = (const float*)d_in[9];
    const float* bn5_g   = (const float*)d_in[10];
    const float* bn5_b   = (const float*)d_in[11];
    const float* convfs_w= (const float*)d_in[12];
    const float* bnfs_g  = (const float*)d_in[13];
    const float* bnfs_b  = (const float*)d_in[14];
    const float* saq_w   = (const float*)d_in[15];
    const float* saq_b   = (const float*)d_in[16];
    const float* sak_w   = (const float*)d_in[17];
    const float* sak_b   = (const float*)d_in[18];
    const float* sac6_w  = (const float*)d_in[19];
    const float* sac6_b  = (const float*)d_in[20];

    float* ws = (float*)d_ws;
    const size_t TEN = (size_t)Bsz * Cch * HWsz;  // 294912
    // ---- persistent region (~11.9 MB) ----
    float* cat    = ws;                            // B*96*HW
    float* f1     = cat + (size_t)Bsz * CIN_CAT * HWsz;
    float* f_s_1  = f1 + TEN;
    float* fg     = f_s_1 + TEN;
    float* fs     = fg + TEN;
    float* sfs    = fs + TEN;
    float* fgl    = sfs + TEN;
    float* t1     = fgl + TEN;
    float* logits = t1 + TEN;              // 9216
    float* xco    = logits + BHW;          // 9216
    float* ksum   = xco + BHW;             // 64 floats reserved
    // ---- shared arena: SA-scratch and conv-scratch never live simultaneously ----
    float* arena  = ksum + 64;
    // SA view (live only inside run_sa): 3*TEN f32 + 32*BHW f32 + 4*TEN bf16 ≈ 7.1 MB
    float* qbuf   = arena;
    float* kT     = qbuf + TEN;
    float* cnb    = kT + TEN;
    float* pmax   = cnb + TEN;                       // 32*9216
    bf16_t* qhi   = (bf16_t*)(pmax + (size_t)NSPLIT * BHW);
    bf16_t* qlo   = qhi + TEN;
    bf16_t* khi   = qlo + TEN;
    bf16_t* klo   = khi + TEN;
    // conv view (live only around conv calls): ≈ 3.7 MB, aliases the SA view
    bf16_t* xthi  = (bf16_t*)arena;                  // BHW*96
    bf16_t* xtlo  = xthi + (size_t)BHW * CIN_CAT;
    bf16_t* wthi  = xtlo + (size_t)BHW * CIN_CAT;    // 9*32*96
    bf16_t* wtlo  = wthi + 9 * 32 * CIN_CAT;
    bf16_t* zbuf  = wtlo + 9 * 32 * CIN_CAT;         // 128 zeros

    const int TPB = 256;
    const int GRID_TEN = (int)((TEN + TPB - 1) / TPB);   // 1152
    const int GRID_MFMA = 144;                            // 576 waves

    // 1. f3 = resize(x3, 192->48) into cat ch[0:32)
    resize_kernel<<<GRID_TEN, TPB, 0, stream>>>(x3, cat, 192, 192, 192, 192 * 192, 0,
                                                191.0f / 47.0f, 191.0f / 47.0f, CIN_CAT, 0);
    // 2. f2 = resize(x2, 96->48) into cat ch[32:64)
    resize_kernel<<<GRID_TEN, TPB, 0, stream>>>(x2, cat, 96, 96, 96, 96 * 96, 0,
                                                95.0f / 47.0f, 95.0f / 47.0f, CIN_CAT, 32);
    // 3. x1 into cat ch[64:96)
    copy_x1_kernel<<<GRID_TEN, TPB, 0, stream>>>(x1, cat);
    zeros_kernel<<<1, 128, 0, stream>>>(zbuf);
    // 4. f1 = bn1(conv1(cat))  via implicit-GEMM MFMA
    prep_w_kernel<<<(9 * 32 * CIN_CAT + 255) / 256, 256, 0, stream>>>(conv1_w, 32, CIN_CAT, wthi, wtlo);
    prep_x_kernel<<<(BHW * CIN_CAT + 255) / 256, 256, 0, stream>>>(cat, nullptr, CIN_CAT, xthi, xtlo);
    conv_mfma_kernel<CIN_CAT, 32, false><<<GRID_MFMA, 256, 0, stream>>>(
        xthi, xtlo, wthi, wtlo, zbuf, bn1_g, bn1_b, nullptr, f1);
    // 5. f_s_1 = resize(f1[:, :, 32:48, 32:48], 16->48)  (chunk idx is always 8)
    resize_kernel<<<GRID_TEN, TPB, 0, stream>>>(f1, f_s_1, 16, 16, Ww, HWsz, 32 * Ww + 32,
                                                15.0f / 47.0f, 15.0f / 47.0f, Cch, 0);

    // SA macro: x -> out
    auto run_sa = [&](const float* xin, float* outp) {
        dim3 g1((BHW + TPB - 1) / TPB, 3);
        qkc_kernel<<<g1, TPB, 0, stream>>>(xin, saq_w, saq_b, sak_w, sak_b, sac6_w,
                                           qbuf, kT, cnb, qhi, qlo, khi, klo);
        ksum_kernel<<<Cch, 256, 0, stream>>>(kT, ksum);
        dim3 g2(36, NSPLIT);
        score_mfma_kernel<<<g2, 256, 0, stream>>>(qhi, qlo, khi, klo, pmax);
        logits_kernel<<<BHW / 256, 256, 0, stream>>>(qbuf, ksum, pmax, logits);
        softmax_kernel<<<Bsz, 256, 0, stream>>>(logits, xco);
        sa_apply_kernel<<<GRID_TEN, TPB, 0, stream>>>(cnb, xco, sac6_b, outp);
    };

    // 6-8. fg = sa(f1); fs = sa(f_s_1); sfs = sa(fs)
    run_sa(f1, fg);
    run_sa(f_s_1, fs);
    run_sa(fs, sfs);

    // 9. fgl = bnfs(convfs(fg + sfs))
    zeros_kernel<<<1, 128, 0, stream>>>(zbuf);
    prep_w_kernel<<<(9 * 32 * Cch + 255) / 256, 256, 0, stream>>>(convfs_w, 32, Cch, wthi, wtlo);
    prep_x_kernel<<<(BHW * Cch + 255) / 256, 256, 0, stream>>>(fg, sfs, Cch, xthi, xtlo);
    conv_mfma_kernel<Cch, 32, false><<<GRID_MFMA, 256, 0, stream>>>(
        xthi, xtlo, wthi, wtlo, zbuf, bnfs_g, bnfs_b, nullptr, fgl);
    // 10. t1 = bn4(conv4(fgl)) + fg
    prep_w_kernel<<<(9 * 32 * Cch + 255) / 256, 256, 0, stream>>>(conv4_w, 32, Cch, wthi, wtlo);
    prep_x_kernel<<<(BHW * Cch + 255) / 256, 256, 0, stream>>>(fgl, nullptr, Cch, xthi, xtlo);
    conv_mfma_kernel<Cch, 32, true><<<GRID_MFMA, 256, 0, stream>>>(
        xthi, xtlo, wthi, wtlo, zbuf, bn4_g, bn4_b, fg, t1);
    // 11. out = bn5(conv5(t1))   (B,1,48,48)
    prep_w_kernel<<<(9 * 32 * Cch + 255) / 256, 256, 0, stream>>>(conv5_w, 1, Cch, wthi, wtlo);
    prep_x_kernel<<<(BHW * Cch + 255) / 256, 256, 0, stream>>>(t1, nullptr, Cch, xthi, xtlo);
    conv_mfma_kernel<Cch, 1, false><<<GRID_MFMA, 256, 0, stream>>>(
        xthi, xtlo, wthi, wtlo, zbuf, bn5_g, bn5_b, nullptr, (float*)d_out);
}